// Round 1
// baseline (1858.155 us; speedup 1.0000x reference)
//
#include <hip/hip_runtime.h>

typedef unsigned short u16;
typedef _Float16 f16x8_t __attribute__((ext_vector_type(8)));
typedef short    i16x8_t __attribute__((ext_vector_type(8)));
typedef short    i16x4_t __attribute__((ext_vector_type(4)));
typedef float    f32x4_t __attribute__((ext_vector_type(4)));

// ---- helpers ---------------------------------------------------------------
static __device__ __forceinline__ u16 f2h(float f) {
  _Float16 h = (_Float16)f;  // RNE
  return __builtin_bit_cast(u16, h);
}
static __device__ __forceinline__ f32x4_t mfma16h(i16x8_t a, i16x8_t b, f32x4_t c) {
  return __builtin_amdgcn_mfma_f32_16x16x32_f16(
      __builtin_bit_cast(f16x8_t, a), __builtin_bit_cast(f16x8_t, b), c, 0, 0, 0);
}
static __device__ __forceinline__ float sigmoidf_(float x) { return 1.f / (1.f + __expf(-x)); }
static __device__ __forceinline__ float tanhf_(float x) { return 1.f - 2.f / (__expf(2.f * x) + 1.f); }

// ---- prep: LSTM weights pre-swizzled into MFMA fragment order --------------
// wpack[dir][tau][kb][lane][8]: tau = jb*4+g (jb = j-block, g = gate),
// kb in [0,12), lane = quad*16+mrow. Element e: n = g*256+jb*16+mrow,
// k = kb*32+quad*8+e; value = k<128 ? Wi[k][n] : Wh[k-128][n].
__global__ __launch_bounds__(256) void prep_wpack(const float* __restrict__ Wi_f,
                                                  const float* __restrict__ Wh_f,
                                                  const float* __restrict__ Wi_r,
                                                  const float* __restrict__ Wh_r,
                                                  u16* __restrict__ wpack) {
  int id = blockIdx.x * 256 + threadIdx.x;
  if (id >= 786432) return;  // 2*64*12*64*8
  int e = id & 7, r = id >> 3;
  int lane = r & 63; r >>= 6;
  int kb = r % 12; r /= 12;
  int tau = r & 63, dir = r >> 6;
  int mrow = lane & 15, quad = lane >> 4;
  int jb = tau >> 2, g = tau & 3;
  int n = g * 256 + jb * 16 + mrow;
  int k = kb * 32 + quad * 8 + e;
  const float* Wi = dir ? Wi_r : Wi_f;
  const float* Wh = dir ? Wh_r : Wh_f;
  float v = (k < 128) ? Wi[k * 1024 + n] : Wh[(k - 128) * 1024 + n];
  wpack[id] = f2h(v);
}

// ---- prep: MLP W^T in f16 (W1[512][256], W2[256][256], W3[256][128]) -------
__global__ __launch_bounds__(256) void prep_small(const float* __restrict__ W1,
                                                  const float* __restrict__ W2,
                                                  const float* __restrict__ W3,
                                                  u16* __restrict__ w1t,
                                                  u16* __restrict__ w2t,
                                                  u16* __restrict__ w3t) {
  int id = blockIdx.x * 256 + threadIdx.x;
  if (id < 131072) { int n = id >> 9, k = id & 511; w1t[id] = f2h(W1[k * 256 + n]); return; }
  id -= 131072;
  if (id < 65536) { int n = id >> 8, k = id & 255; w2t[id] = f2h(W2[k * 256 + n]); return; }
  id -= 65536;
  if (id < 32768) { int n = id >> 8, k = id & 255; w3t[id] = f2h(W3[k * 128 + n]); }
}

// ---- bidirectional LSTM v4 -------------------------------------------------
// 64 blocks (32/dir, M=16 batch rows), 512 threads = 8 waves (2/SIMD ->
// 256-reg budget). Wave w owns taus 8w..8w+7 (j-blocks {2w,2w+1} x 4 gates) ->
// in-register f/i/a/o update with c[2][4]. kb<2 slice (128 KB) LDS-resident;
// kb 2..11 double-buffered in registers (wb[2][10]), prefetched one tau ahead
// (the ti=7 prefetch wraps to next step's tau0 -- weights are t-invariant).
// x row prefetched into registers a full step ahead (issued right AFTER the
// barrier so the compiler's pre-barrier vmcnt(0) drain is free).
__global__ __launch_bounds__(512, 2) void lstm_kernel(
    const float* __restrict__ x0, const u16* __restrict__ wpack,
    const float* __restrict__ bi_f, const float* __restrict__ bh_f,
    const float* __restrict__ bi_r, const float* __restrict__ bh_r,
    u16* __restrict__ x1) {
  __shared__ __align__(16) u16 lw[64][2][64][8];   // 128 KB resident weights
  __shared__ __align__(16) u16 ax[2][16][136];     // x_t panel (f16)
  __shared__ __align__(16) u16 ah[2][16][264];     // h panel (f16)

  const int tid = threadIdx.x;
  const int lane = tid & 63;
  const int w = tid >> 6;               // wave id 0..7
  const int dir = blockIdx.x >> 5;
  const int b0 = (blockIdx.x & 31) * 16;
  const u16* wpk = wpack + (size_t)dir * (64 * 12 * 64 * 8);
  const float* bi = dir ? bi_r : bi_f;
  const float* bh = dir ? bh_r : bh_f;
  const int mrow = lane & 15, quad = lane >> 4;
  const int jb0 = w << 1;               // this wave's first j-block

  float bias_[2][4];
#pragma unroll
  for (int j = 0; j < 2; ++j)
#pragma unroll
    for (int g = 0; g < 4; ++g) {
      int n = g * 256 + (jb0 + j) * 16 + mrow;
      bias_[j][g] = bi[n] + bh[n];
    }
  float c[2][4] = {};

  // preload resident kb<2 weight slice: 8192 frags of 16 B, 16 per thread
#pragma unroll
  for (int r = 0; r < 16; ++r) {
    int d = r * 512 + tid;                  // frag index: tau*128 + kb*64 + lane
    int ltau = d >> 7, lkb = (d >> 6) & 1, llane = d & 63;
    *(i16x8_t*)&lw[ltau][lkb][llane][0] =
        *(const i16x8_t*)(wpk + (((size_t)ltau * 12 + lkb) * 64 + llane) * 8);
  }
  // h_{-1} = 0
  for (int i = tid; i < 2 * 16 * 264; i += 512) ((u16*)ah)[i] = 0;

  // streamed-weight base for this wave (taus 8w..8w+7 are contiguous)
  const u16* wstream = wpk + (size_t)(jb0 << 2) * 6144 + lane * 8;

  // prologue: fill buffer 0 with tau0's streamed frags (kb 2..11)
  i16x8_t wb[2][10];
#pragma unroll
  for (int kk = 0; kk < 10; ++kk)
    wb[0][kk] = *(const i16x8_t*)(wstream + (kk + 2) * 512);

  // x prefetch registers: one float4 (= 4 cols of one row) per thread
  const int xrow = tid >> 5, xcc = (tid & 31) * 4;
  const float* xbase = x0 + (size_t)(b0 + xrow) * 16384 + xcc;
  float4 xv = *(const float4*)(xbase + (size_t)(dir ? 127 : 0) * 128);

  for (int t = 0; t < 128; ++t) {
    const int par = t & 1;
    // write prefetched x_t -> ax[par]
    {
      i16x4_t x4;
      x4[0] = (short)f2h(xv.x); x4[1] = (short)f2h(xv.y);
      x4[2] = (short)f2h(xv.z); x4[3] = (short)f2h(xv.w);
      *(i16x4_t*)&ax[par][xrow][xcc] = x4;
    }
    __syncthreads();  // orders: x stage, preload (t=0), prev h-writes, flush reads

    // issue next step's x load now (full step of latency to hide)
    if (t < 127) {
      int teff = dir ? (126 - t) : (t + 1);
      xv = *(const float4*)(xbase + (size_t)teff * 128);
    }

    // coalesced flush h_{t-1} -> x1 (16 B/thread)
    if (t > 0) {
      int fm = tid >> 5, fj = (tid & 31) * 8;
      i16x8_t hh = *(const i16x8_t*)&ah[par ^ 1][fm][fj];
      *(i16x8_t*)(x1 + ((size_t)((b0 + fm) * 128 + (t - 1))) * 512 + dir * 256 + fj) = hh;
    }

    // A-fragments: k<128 from x panel, k>=128 from h panel (shared by 8 taus)
    i16x8_t af[12];
#pragma unroll
    for (int kb = 0; kb < 4; ++kb)
      af[kb] = *(const i16x8_t*)&ax[par][mrow][kb * 32 + quad * 8];
#pragma unroll
    for (int kb = 4; kb < 12; ++kb)
      af[kb] = *(const i16x8_t*)&ah[par ^ 1][mrow][(kb - 4) * 32 + quad * 8];

    f32x4_t acc[2][4];
#pragma unroll
    for (int ti = 0; ti < 8; ++ti) {
      const int tau = (jb0 << 2) | ti;
      // prefetch next tau's streamed frags into the other buffer
      // (ti==7 wraps to tau0 for the NEXT timestep -- weights are t-invariant)
      const int nti = (ti + 1) & 7;
#pragma unroll
      for (int kk = 0; kk < 10; ++kk)
        wb[(ti + 1) & 1][kk] =
            *(const i16x8_t*)(wstream + nti * 6144 + (kk + 2) * 512);
      i16x8_t wf0 = *(const i16x8_t*)&lw[tau][0][lane][0];
      i16x8_t wf1 = *(const i16x8_t*)&lw[tau][1][lane][0];
      float bv = bias_[ti >> 2][ti & 3];
      f32x4_t a = {bv, bv, bv, bv};
      a = mfma16h(af[0], wf0, a);
      a = mfma16h(af[1], wf1, a);
#pragma unroll
      for (int kb = 2; kb < 12; ++kb)
        a = mfma16h(af[kb], wb[ti & 1][kb - 2], a);
      acc[ti >> 2][ti & 3] = a;
    }

    // in-register gate update; lane holds (m = quad*4+r, j = (jb0+j')*16+mrow)
#pragma unroll
    for (int j = 0; j < 2; ++j) {
      const int jcol = (jb0 + j) * 16 + mrow;
#pragma unroll
      for (int r = 0; r < 4; ++r) {
        float fv = sigmoidf_(acc[j][0][r]);
        float iv = sigmoidf_(acc[j][1][r]);
        float av = tanhf_(acc[j][2][r]);
        float ov = sigmoidf_(acc[j][3][r]);
        float cv = fv * c[j][r] + iv * av;
        c[j][r] = cv;
        ah[par][(quad << 2) | r][jcol] = f2h(ov * tanhf_(cv));
      }
    }
  }
  // epilogue: flush h_127 (par of t=127 is 1)
  __syncthreads();
  {
    int fm = tid >> 5, fj = (tid & 31) * 8;
    i16x8_t hh = *(const i16x8_t*)&ah[1][fm][fj];
    *(i16x8_t*)(x1 + ((size_t)((b0 + fm) * 128 + 127)) * 512 + dir * 256 + fj) = hh;
  }
}

// ---- fused MLP + heads (unchanged — passing) ------------------------------
__global__ __launch_bounds__(512, 1) void mlp_kernel(
    const u16* __restrict__ x1, const u16* __restrict__ w1t,
    const u16* __restrict__ w2t, const u16* __restrict__ w3t,
    const float* __restrict__ b1, const float* __restrict__ b2,
    const float* __restrict__ b3, float* __restrict__ out) {
  __shared__ __align__(16) u16 X2[128][264];
  __shared__ __align__(16) u16 X3[128][264];
  const int tid = threadIdx.x;
  const int lane = tid & 63, wv = tid >> 6;
  const int mrow = lane & 15, quad = lane >> 4;
  const int r0 = blockIdx.x * 128;
  const f32x4_t zero4 = {0.f, 0.f, 0.f, 0.f};

  // stage 1: X2[128][256] = leaky(x1[128,512] @ W1 + b1)
  {
    f32x4_t acc[16];
#pragma unroll
    for (int n = 0; n < 16; ++n) acc[n] = zero4;
    for (int kb = 0; kb < 16; ++kb) {
      int k = kb * 32 + quad * 8;
      i16x8_t a = *(const i16x8_t*)(x1 + (size_t)(r0 + wv * 16 + mrow) * 512 + k);
#pragma unroll
      for (int n = 0; n < 16; ++n) {
        i16x8_t b = *(const i16x8_t*)(w1t + (n * 16 + mrow) * 512 + k);
        acc[n] = mfma16h(a, b, acc[n]);
      }
    }
#pragma unroll
    for (int n = 0; n < 16; ++n)
#pragma unroll
      for (int r = 0; r < 4; ++r) {
        int m = wv * 16 + quad * 4 + r;
        int col = n * 16 + mrow;
        float v = acc[n][r] + b1[col];
        v = v > 0.f ? v : 0.1f * v;
        X2[m][col] = f2h(v);
      }
  }
  __syncthreads();

  // stage 2: X3[128][256] = leaky(X2 @ W2 + b2), K=256
  {
    f32x4_t acc[16];
#pragma unroll
    for (int n = 0; n < 16; ++n) acc[n] = zero4;
#pragma unroll
    for (int kb = 0; kb < 8; ++kb) {
      int k = kb * 32 + quad * 8;
      i16x8_t a = *(const i16x8_t*)&X2[wv * 16 + mrow][k];
#pragma unroll
      for (int n = 0; n < 16; ++n) {
        i16x8_t b = *(const i16x8_t*)(w2t + (n * 16 + mrow) * 256 + k);
        acc[n] = mfma16h(a, b, acc[n]);
      }
    }
#pragma unroll
    for (int n = 0; n < 16; ++n)
#pragma unroll
      for (int r = 0; r < 4; ++r) {
        int m = wv * 16 + quad * 4 + r;
        int col = n * 16 + mrow;
        float v = acc[n][r] + b2[col];
        v = v > 0.f ? v : 0.1f * v;
        X3[m][col] = f2h(v);
      }
  }
  __syncthreads();

  // stage 3: XF[128][128] = X3 @ W3 + b3 (fp32; overlays dead X2)
  float (*XF)[130] = (float (*)[130]) & X2[0][0];
  {
    f32x4_t acc[8];
#pragma unroll
    for (int n = 0; n < 8; ++n) acc[n] = zero4;
#pragma unroll
    for (int kb = 0; kb < 8; ++kb) {
      int k = kb * 32 + quad * 8;
      i16x8_t a = *(const i16x8_t*)&X3[wv * 16 + mrow][k];
#pragma unroll
      for (int n = 0; n < 8; ++n) {
        i16x8_t b = *(const i16x8_t*)(w3t + (n * 16 + mrow) * 256 + k);
        acc[n] = mfma16h(a, b, acc[n]);
      }
    }
#pragma unroll
    for (int n = 0; n < 8; ++n)
#pragma unroll
      for (int r = 0; r < 4; ++r) {
        int m = wv * 16 + quad * 4 + r;
        int col = n * 16 + mrow;
        XF[m][col] = acc[n][r] + b3[col];
      }
  }
  __syncthreads();

  // heads: cols 0:64 sigmoid; softmax over [64,72), [72,88), [88,128)
  if (tid < 128) {
    int row = tid;
    float* xr = XF[row];
    float* op = out + (size_t)(r0 + row) * 128;
    for (int cc = 0; cc < 64; ++cc) op[cc] = sigmoidf_(xr[cc]);
  } else if (tid < 256) {
    int row = tid - 128;
    float* xr = XF[row];
    float* op = out + (size_t)(r0 + row) * 128;
    const int s0s[3] = {64, 72, 88};
    const int s1s[3] = {72, 88, 128};
    for (int s = 0; s < 3; ++s) {
      int s0 = s0s[s], s1 = s1s[s];
      float mx = xr[s0];
      for (int q = s0 + 1; q < s1; ++q) mx = fmaxf(mx, xr[q]);
      float sum = 0.f;
      for (int q = s0; q < s1; ++q) { float e = __expf(xr[q] - mx); xr[q] = e; sum += e; }
      float inv = 1.f / sum;
      for (int q = s0; q < s1; ++q) op[q] = xr[q] * inv;
    }
  }
}

// ---- launch ----------------------------------------------------------------
extern "C" void kernel_launch(void* const* d_in, const int* in_sizes, int n_in,
                              void* d_out, int out_size, void* d_ws, size_t ws_size,
                              hipStream_t stream) {
  const float* x0   = (const float*)d_in[0];
  const float* Wi_f = (const float*)d_in[1];
  const float* bi_f = (const float*)d_in[2];
  const float* Wh_f = (const float*)d_in[3];
  const float* bh_f = (const float*)d_in[4];
  const float* Wi_r = (const float*)d_in[5];
  const float* bi_r = (const float*)d_in[6];
  const float* Wh_r = (const float*)d_in[7];
  const float* bh_r = (const float*)d_in[8];
  const float* W1 = (const float*)d_in[9];
  const float* b1 = (const float*)d_in[10];
  const float* W2 = (const float*)d_in[11];
  const float* b2 = (const float*)d_in[12];
  const float* W3 = (const float*)d_in[13];
  const float* b3 = (const float*)d_in[14];
  float* out = (float*)d_out;

  char* ws = (char*)d_ws;
  u16* w1t   = (u16*)(ws + 0);         // 262144 B
  u16* w2t   = (u16*)(ws + 262144);    // 131072 B
  u16* w3t   = (u16*)(ws + 393216);    // 65536 B
  u16* wpack = (u16*)(ws + 458752);    // 1572864 B
  u16* x1    = (u16*)(ws + 2031616);   // 67108864 B

  hipLaunchKernelGGL(prep_wpack, dim3(3072), dim3(256), 0, stream,
                     Wi_f, Wh_f, Wi_r, Wh_r, wpack);
  hipLaunchKernelGGL(prep_small, dim3(896), dim3(256), 0, stream,
                     W1, W2, W3, w1t, w2t, w3t);
  hipLaunchKernelGGL(lstm_kernel, dim3(64), dim3(512), 0, stream,
                     x0, wpack, bi_f, bh_f, bi_r, bh_r, x1);
  hipLaunchKernelGGL(mlp_kernel, dim3(512), dim3(512), 0, stream,
                     x1, w1t, w2t, w3t, b1, b2, b3, out);
}

// Round 2
// 1393.207 us; speedup vs baseline: 1.3337x; 1.3337x over previous
//
#include <hip/hip_runtime.h>

typedef unsigned short u16;
typedef _Float16 f16x8_t __attribute__((ext_vector_type(8)));
typedef short    i16x8_t __attribute__((ext_vector_type(8)));
typedef short    i16x4_t __attribute__((ext_vector_type(4)));
typedef float    f32x4_t __attribute__((ext_vector_type(4)));

// ---- helpers ---------------------------------------------------------------
static __device__ __forceinline__ u16 f2h(float f) {
  _Float16 h = (_Float16)f;  // RNE
  return __builtin_bit_cast(u16, h);
}
static __device__ __forceinline__ f32x4_t mfma16h(i16x8_t a, i16x8_t b, f32x4_t c) {
  return __builtin_amdgcn_mfma_f32_16x16x32_f16(
      __builtin_bit_cast(f16x8_t, a), __builtin_bit_cast(f16x8_t, b), c, 0, 0, 0);
}
static __device__ __forceinline__ float sigmoidf_(float x) { return 1.f / (1.f + __expf(-x)); }
static __device__ __forceinline__ float tanhf_(float x) { return 1.f - 2.f / (__expf(2.f * x) + 1.f); }

// ---- prep: LSTM weights pre-swizzled into MFMA fragment order --------------
// wpack[dir][tau][kb][lane][8]: tau = jb*4+g (jb = j-block, g = gate),
// kb in [0,12), lane = quad*16+mrow. Element e: n = g*256+jb*16+mrow,
// k = kb*32+quad*8+e; value = k<128 ? Wi[k][n] : Wh[k-128][n].
__global__ __launch_bounds__(256) void prep_wpack(const float* __restrict__ Wi_f,
                                                  const float* __restrict__ Wh_f,
                                                  const float* __restrict__ Wi_r,
                                                  const float* __restrict__ Wh_r,
                                                  u16* __restrict__ wpack) {
  int id = blockIdx.x * 256 + threadIdx.x;
  if (id >= 786432) return;  // 2*64*12*64*8
  int e = id & 7, r = id >> 3;
  int lane = r & 63; r >>= 6;
  int kb = r % 12; r /= 12;
  int tau = r & 63, dir = r >> 6;
  int mrow = lane & 15, quad = lane >> 4;
  int jb = tau >> 2, g = tau & 3;
  int n = g * 256 + jb * 16 + mrow;
  int k = kb * 32 + quad * 8 + e;
  const float* Wi = dir ? Wi_r : Wi_f;
  const float* Wh = dir ? Wh_r : Wh_f;
  float v = (k < 128) ? Wi[k * 1024 + n] : Wh[(k - 128) * 1024 + n];
  wpack[id] = f2h(v);
}

// ---- prep: MLP W^T in f16 (W1[512][256], W2[256][256], W3[256][128]) -------
__global__ __launch_bounds__(256) void prep_small(const float* __restrict__ W1,
                                                  const float* __restrict__ W2,
                                                  const float* __restrict__ W3,
                                                  u16* __restrict__ w1t,
                                                  u16* __restrict__ w2t,
                                                  u16* __restrict__ w3t) {
  int id = blockIdx.x * 256 + threadIdx.x;
  if (id < 131072) { int n = id >> 9, k = id & 511; w1t[id] = f2h(W1[k * 256 + n]); return; }
  id -= 131072;
  if (id < 65536) { int n = id >> 8, k = id & 255; w2t[id] = f2h(W2[k * 256 + n]); return; }
  id -= 65536;
  if (id < 32768) { int n = id >> 8, k = id & 255; w3t[id] = f2h(W3[k * 128 + n]); }
}

// ---- bidirectional LSTM v5: chunked x-projection + resident Wh -------------
// 64 blocks (32/dir, M=16 rows), 512 threads = 8 waves (2/SIMD, 256-reg cap).
// Wave w owns taus 8w..8w+7. Per 16-step chunk:
//   phase G: P[s][tau] = bias + x_t@Wi (kb 0..3) via MFMA, Wi frags in regs
//            (reused over 16 t), stored f32 to a 1 MB/block global slab.
//            f32 round-trip is exact -> numerics bit-identical to v4.
//   phase R: 16 recurrence steps; acc = P + h@Wh. Wh residency: kb 4,5 in
//            LDS (128 KB), kb 6..9 in regs (128 VGPR/wave, reloaded per
//            chunk), kb 10,11 streamed (L2-hot, 16 KB/wave/step).
// Streamed bytes/CU/step: 640 KB (v4) -> 192 KB (128 Wh + 64 P).
__global__ __launch_bounds__(512, 2) void lstm_kernel(
    const float* __restrict__ x0, const u16* __restrict__ wpack,
    const float* __restrict__ bi_f, const float* __restrict__ bh_f,
    const float* __restrict__ bi_r, const float* __restrict__ bh_r,
    u16* __restrict__ x1, float* __restrict__ pbuf) {
  __shared__ __align__(16) u16 lwh[64][2][64][8];  // Wh kb 4,5 resident (128 KB)
  __shared__ __align__(16) u16 ah[2][16][264];     // h panel (f16)
  __shared__ __align__(16) u16 xs[2][16][136];     // x staging for phase G (2 t)

  const int tid = threadIdx.x;
  const int lane = tid & 63;
  const int w = tid >> 6;               // wave id 0..7
  const int dir = blockIdx.x >> 5;
  const int b0 = (blockIdx.x & 31) * 16;
  const u16* wpk = wpack + (size_t)dir * (64 * 12 * 64 * 8);
  const float* bi = dir ? bi_r : bi_f;
  const float* bh = dir ? bh_r : bh_f;
  const int mrow = lane & 15, quad = lane >> 4;
  const int jb0 = w << 1;
  float* pblk = pbuf + ((size_t)blockIdx.x << 18);  // 1 MB slab per block

  float bias_[8];
#pragma unroll
  for (int ti = 0; ti < 8; ++ti) {
    int tau = 8 * w + ti;
    int n = (tau & 3) * 256 + (tau >> 2) * 16 + mrow;
    bias_[ti] = bi[n] + bh[n];
  }
  float c_[2][4] = {};

  // LDS-resident Wh slices kb 4,5: 8192 frags of 16 B, 16 per thread
#pragma unroll
  for (int r = 0; r < 16; ++r) {
    int d = r * 512 + tid;                  // frag index: tau*128 + kb*64 + lane
    int ltau = d >> 7, lkb = (d >> 6) & 1, llane = d & 63;
    *(i16x8_t*)&lwh[ltau][lkb][llane][0] =
        *(const i16x8_t*)(wpk + (((size_t)ltau * 12 + 4 + lkb) * 64 + llane) * 8);
  }
  // h_{-1} = 0 (both parities)
  for (int i = tid; i < 2 * 16 * 264; i += 512) ((u16*)ah)[i] = 0;
  __syncthreads();

  i16x8_t wreg[8][4];  // phase G: Wi kb0..3; phase R: Wh kb6..9

  for (int chunk = 0; chunk < 8; ++chunk) {
    // ================= phase G: P = bias + x@Wi for 16 steps ================
#pragma unroll
    for (int ti = 0; ti < 8; ++ti)
#pragma unroll
      for (int kb = 0; kb < 4; ++kb)
        wreg[ti][kb] =
            *(const i16x8_t*)(wpk + (((size_t)(8 * w + ti) * 12 + kb) * 64 + lane) * 8);

    for (int tp = 0; tp < 8; ++tp) {
      {  // stage 2 timesteps of x into xs (f16)
        int tt0 = tid >> 8;                 // 0..1
        int row = (tid >> 4) & 15;
        int c8 = (tid & 15) * 8;
        int t = chunk * 16 + tp * 2 + tt0;
        int teff = dir ? 127 - t : t;
        const float* xp = x0 + ((size_t)(b0 + row) * 128 + teff) * 128 + c8;
        float4 va = *(const float4*)(xp);
        float4 vb = *(const float4*)(xp + 4);
        i16x8_t xv8;
        xv8[0] = (short)f2h(va.x); xv8[1] = (short)f2h(va.y);
        xv8[2] = (short)f2h(va.z); xv8[3] = (short)f2h(va.w);
        xv8[4] = (short)f2h(vb.x); xv8[5] = (short)f2h(vb.y);
        xv8[6] = (short)f2h(vb.z); xv8[7] = (short)f2h(vb.w);
        *(i16x8_t*)&xs[tt0][row][c8] = xv8;
      }
      __syncthreads();
#pragma unroll
      for (int tt = 0; tt < 2; ++tt) {
        i16x8_t afx[4];
#pragma unroll
        for (int kb = 0; kb < 4; ++kb)
          afx[kb] = *(const i16x8_t*)&xs[tt][mrow][kb * 32 + quad * 8];
        int sloc = tp * 2 + tt;
#pragma unroll
        for (int ti = 0; ti < 8; ++ti) {
          float bv = bias_[ti];
          f32x4_t a = {bv, bv, bv, bv};
          a = mfma16h(afx[0], wreg[ti][0], a);
          a = mfma16h(afx[1], wreg[ti][1], a);
          a = mfma16h(afx[2], wreg[ti][2], a);
          a = mfma16h(afx[3], wreg[ti][3], a);
          *(f32x4_t*)(pblk + (((size_t)sloc * 64 + 8 * w + ti) * 64 + lane) * 4) = a;
        }
      }
      __syncthreads();  // xs reads done before next stage overwrites
    }

    // reload wreg with resident Wh slices kb 6..9
#pragma unroll
    for (int ti = 0; ti < 8; ++ti)
#pragma unroll
      for (int kk = 0; kk < 4; ++kk)
        wreg[ti][kk] =
            *(const i16x8_t*)(wpk + (((size_t)(8 * w + ti) * 12 + 6 + kk) * 64 + lane) * 8);

    // ================= phase R: 16 recurrence steps ========================
    for (int s = 0; s < 16; ++s) {
      const int t = chunk * 16 + s;
      const int par = t & 1;
      __syncthreads();  // orders prev h-writes / G stores vs this step's reads

      // coalesced flush h_{t-1} -> x1 (16 B/thread)
      if (t > 0) {
        int fm = tid >> 5, fj = (tid & 31) * 8;
        i16x8_t hh = *(const i16x8_t*)&ah[par ^ 1][fm][fj];
        *(i16x8_t*)(x1 + ((size_t)((b0 + fm) * 128 + (t - 1))) * 512 + dir * 256 + fj) = hh;
      }

      // h fragments (shared across this wave's 8 taus)
      i16x8_t af[8];
#pragma unroll
      for (int kb = 0; kb < 8; ++kb)
        af[kb] = *(const i16x8_t*)&ah[par ^ 1][mrow][kb * 32 + quad * 8];

      // pipeline: P frag + 2 streamed Wh frags, 1 tau ahead
      f32x4_t pf[2];
      i16x8_t wA[2], wB[2];
      {
        const int tau0 = 8 * w;
        pf[0] = *(const f32x4_t*)(pblk + (((size_t)s * 64 + tau0) * 64 + lane) * 4);
        wA[0] = *(const i16x8_t*)(wpk + (((size_t)tau0 * 12 + 10) * 64 + lane) * 8);
        wB[0] = *(const i16x8_t*)(wpk + (((size_t)tau0 * 12 + 11) * 64 + lane) * 8);
      }
#pragma unroll
      for (int j = 0; j < 2; ++j) {
        f32x4_t acc4[4];
#pragma unroll
        for (int g = 0; g < 4; ++g) {
          const int ti = j * 4 + g, cur = ti & 1, nxt = cur ^ 1;
          if (ti < 7) {
            const int taun = 8 * w + ti + 1;
            pf[nxt] = *(const f32x4_t*)(pblk + (((size_t)s * 64 + taun) * 64 + lane) * 4);
            wA[nxt] = *(const i16x8_t*)(wpk + (((size_t)taun * 12 + 10) * 64 + lane) * 8);
            wB[nxt] = *(const i16x8_t*)(wpk + (((size_t)taun * 12 + 11) * 64 + lane) * 8);
          }
          const int tau = 8 * w + ti;
          f32x4_t a = pf[cur];
          a = mfma16h(af[0], *(const i16x8_t*)&lwh[tau][0][lane][0], a);
          a = mfma16h(af[1], *(const i16x8_t*)&lwh[tau][1][lane][0], a);
          a = mfma16h(af[2], wreg[ti][0], a);
          a = mfma16h(af[3], wreg[ti][1], a);
          a = mfma16h(af[4], wreg[ti][2], a);
          a = mfma16h(af[5], wreg[ti][3], a);
          a = mfma16h(af[6], wA[cur], a);
          a = mfma16h(af[7], wB[cur], a);
          acc4[g] = a;
        }
        // in-register gate update; lane holds (m = quad*4+r, j-col)
        const int jcol = (jb0 + j) * 16 + mrow;
#pragma unroll
        for (int r = 0; r < 4; ++r) {
          float fv = sigmoidf_(acc4[0][r]);
          float iv = sigmoidf_(acc4[1][r]);
          float av = tanhf_(acc4[2][r]);
          float ov = sigmoidf_(acc4[3][r]);
          float cv = fv * c_[j][r] + iv * av;
          c_[j][r] = cv;
          ah[par][(quad << 2) | r][jcol] = f2h(ov * tanhf_(cv));
        }
      }
    }
  }
  // epilogue: flush h_127 (par of t=127 is 1)
  __syncthreads();
  {
    int fm = tid >> 5, fj = (tid & 31) * 8;
    i16x8_t hh = *(const i16x8_t*)&ah[1][fm][fj];
    *(i16x8_t*)(x1 + ((size_t)((b0 + fm) * 128 + 127)) * 512 + dir * 256 + fj) = hh;
  }
}

// ---- fused MLP + heads (unchanged — passing) ------------------------------
__global__ __launch_bounds__(512, 1) void mlp_kernel(
    const u16* __restrict__ x1, const u16* __restrict__ w1t,
    const u16* __restrict__ w2t, const u16* __restrict__ w3t,
    const float* __restrict__ b1, const float* __restrict__ b2,
    const float* __restrict__ b3, float* __restrict__ out) {
  __shared__ __align__(16) u16 X2[128][264];
  __shared__ __align__(16) u16 X3[128][264];
  const int tid = threadIdx.x;
  const int lane = tid & 63, wv = tid >> 6;
  const int mrow = lane & 15, quad = lane >> 4;
  const int r0 = blockIdx.x * 128;
  const f32x4_t zero4 = {0.f, 0.f, 0.f, 0.f};

  // stage 1: X2[128][256] = leaky(x1[128,512] @ W1 + b1)
  {
    f32x4_t acc[16];
#pragma unroll
    for (int n = 0; n < 16; ++n) acc[n] = zero4;
    for (int kb = 0; kb < 16; ++kb) {
      int k = kb * 32 + quad * 8;
      i16x8_t a = *(const i16x8_t*)(x1 + (size_t)(r0 + wv * 16 + mrow) * 512 + k);
#pragma unroll
      for (int n = 0; n < 16; ++n) {
        i16x8_t b = *(const i16x8_t*)(w1t + (n * 16 + mrow) * 512 + k);
        acc[n] = mfma16h(a, b, acc[n]);
      }
    }
#pragma unroll
    for (int n = 0; n < 16; ++n)
#pragma unroll
      for (int r = 0; r < 4; ++r) {
        int m = wv * 16 + quad * 4 + r;
        int col = n * 16 + mrow;
        float v = acc[n][r] + b1[col];
        v = v > 0.f ? v : 0.1f * v;
        X2[m][col] = f2h(v);
      }
  }
  __syncthreads();

  // stage 2: X3[128][256] = leaky(X2 @ W2 + b2), K=256
  {
    f32x4_t acc[16];
#pragma unroll
    for (int n = 0; n < 16; ++n) acc[n] = zero4;
#pragma unroll
    for (int kb = 0; kb < 8; ++kb) {
      int k = kb * 32 + quad * 8;
      i16x8_t a = *(const i16x8_t*)&X2[wv * 16 + mrow][k];
#pragma unroll
      for (int n = 0; n < 16; ++n) {
        i16x8_t b = *(const i16x8_t*)(w2t + (n * 16 + mrow) * 256 + k);
        acc[n] = mfma16h(a, b, acc[n]);
      }
    }
#pragma unroll
    for (int n = 0; n < 16; ++n)
#pragma unroll
      for (int r = 0; r < 4; ++r) {
        int m = wv * 16 + quad * 4 + r;
        int col = n * 16 + mrow;
        float v = acc[n][r] + b2[col];
        v = v > 0.f ? v : 0.1f * v;
        X3[m][col] = f2h(v);
      }
  }
  __syncthreads();

  // stage 3: XF[128][128] = X3 @ W3 + b3 (fp32; overlays dead X2)
  float (*XF)[130] = (float (*)[130]) & X2[0][0];
  {
    f32x4_t acc[8];
#pragma unroll
    for (int n = 0; n < 8; ++n) acc[n] = zero4;
#pragma unroll
    for (int kb = 0; kb < 8; ++kb) {
      int k = kb * 32 + quad * 8;
      i16x8_t a = *(const i16x8_t*)&X3[wv * 16 + mrow][k];
#pragma unroll
      for (int n = 0; n < 8; ++n) {
        i16x8_t b = *(const i16x8_t*)(w3t + (n * 16 + mrow) * 256 + k);
        acc[n] = mfma16h(a, b, acc[n]);
      }
    }
#pragma unroll
    for (int n = 0; n < 8; ++n)
#pragma unroll
      for (int r = 0; r < 4; ++r) {
        int m = wv * 16 + quad * 4 + r;
        int col = n * 16 + mrow;
        XF[m][col] = acc[n][r] + b3[col];
      }
  }
  __syncthreads();

  // heads: cols 0:64 sigmoid; softmax over [64,72), [72,88), [88,128)
  if (tid < 128) {
    int row = tid;
    float* xr = XF[row];
    float* op = out + (size_t)(r0 + row) * 128;
    for (int cc = 0; cc < 64; ++cc) op[cc] = sigmoidf_(xr[cc]);
  } else if (tid < 256) {
    int row = tid - 128;
    float* xr = XF[row];
    float* op = out + (size_t)(r0 + row) * 128;
    const int s0s[3] = {64, 72, 88};
    const int s1s[3] = {72, 88, 128};
    for (int s = 0; s < 3; ++s) {
      int s0 = s0s[s], s1 = s1s[s];
      float mx = xr[s0];
      for (int q = s0 + 1; q < s1; ++q) mx = fmaxf(mx, xr[q]);
      float sum = 0.f;
      for (int q = s0; q < s1; ++q) { float e = __expf(xr[q] - mx); xr[q] = e; sum += e; }
      float inv = 1.f / sum;
      for (int q = s0; q < s1; ++q) op[q] = xr[q] * inv;
    }
  }
}

// ---- launch ----------------------------------------------------------------
extern "C" void kernel_launch(void* const* d_in, const int* in_sizes, int n_in,
                              void* d_out, int out_size, void* d_ws, size_t ws_size,
                              hipStream_t stream) {
  const float* x0   = (const float*)d_in[0];
  const float* Wi_f = (const float*)d_in[1];
  const float* bi_f = (const float*)d_in[2];
  const float* Wh_f = (const float*)d_in[3];
  const float* bh_f = (const float*)d_in[4];
  const float* Wi_r = (const float*)d_in[5];
  const float* bi_r = (const float*)d_in[6];
  const float* Wh_r = (const float*)d_in[7];
  const float* bh_r = (const float*)d_in[8];
  const float* W1 = (const float*)d_in[9];
  const float* b1 = (const float*)d_in[10];
  const float* W2 = (const float*)d_in[11];
  const float* b2 = (const float*)d_in[12];
  const float* W3 = (const float*)d_in[13];
  const float* b3 = (const float*)d_in[14];
  float* out = (float*)d_out;

  char* ws = (char*)d_ws;
  u16* w1t   = (u16*)(ws + 0);         // 262144 B
  u16* w2t   = (u16*)(ws + 262144);    // 131072 B
  u16* w3t   = (u16*)(ws + 393216);    // 65536 B
  u16* wpack = (u16*)(ws + 458752);    // 1572864 B
  u16* x1    = (u16*)(ws + 2031616);   // 67108864 B
  float* pbuf = (float*)(ws + 69140480);  // 67108864 B (64 blocks x 1 MB)

  hipLaunchKernelGGL(prep_wpack, dim3(3072), dim3(256), 0, stream,
                     Wi_f, Wh_f, Wi_r, Wh_r, wpack);
  hipLaunchKernelGGL(prep_small, dim3(896), dim3(256), 0, stream,
                     W1, W2, W3, w1t, w2t, w3t);
  hipLaunchKernelGGL(lstm_kernel, dim3(64), dim3(512), 0, stream,
                     x0, wpack, bi_f, bh_f, bi_r, bh_r, x1, pbuf);
  hipLaunchKernelGGL(mlp_kernel, dim3(512), dim3(512), 0, stream,
                     x1, w1t, w2t, w3t, b1, b2, b3, out);
}